// Round 22
// baseline (313.347 us; speedup 1.0000x reference)
//
#include <hip/hip_runtime.h>
#include <math.h>

constexpr int B = 4, C = 256, CC = 32, H = 64, W = 64, HW = H * W;
constexpr int G = 8, K = 9, GN = 32, CPG = C / GN;   // CPG = 8
constexpr int OFFC = 3 * G * K;                       // 216

typedef __attribute__((ext_vector_type(8))) short short8;
typedef __attribute__((ext_vector_type(4))) float f32x4;

__device__ inline short f2bf(float f) {
  unsigned u = __builtin_bit_cast(unsigned, f);
  return (short)((u + 0x7FFFu + ((u >> 16) & 1u)) >> 16);
}
__device__ inline float bf2f(short s) {
  unsigned u = ((unsigned)(unsigned short)s) << 16;
  return __builtin_bit_cast(float, u);
}

// ---------------- merged prep: weight transforms (K-block-major) + zero ------
__global__ void k_prep(const float* __restrict__ w1a, short* __restrict__ wT1a,
                       const float* __restrict__ w1c, short* __restrict__ wT1c,
                       const float* __restrict__ w2, short* __restrict__ wT2,
                       const float* __restrict__ woff, short* __restrict__ wToff,
                       const float* __restrict__ wdcn, short* __restrict__ wTd,
                       float* __restrict__ sbuf) {
  int id = blockIdx.x * 256 + threadIdx.x;
  if (id < 73728) {
    int o = id / 288, ci = id % 288;
    wT1a[(((size_t)(ci >> 5) * 256) + o) * 32 + (ci & 31)] = f2bf(w1a[id]);
  } else if (id < 139264) {
    int i = id - 73728;
    int o = i >> 8, ci = i & 255;
    wT1c[(((size_t)(ci >> 5) * 256) + o) * 32 + (ci & 31)] = f2bf(w1c[i]);
  } else if (id < 204800) {
    int i = id - 139264;
    int o = i >> 8, ci = i & 255;
    #pragma unroll
    for (int k = 0; k < 9; ++k)
      wT2[((((size_t)(ci >> 5) * 9 + k) * 256) + o) * 32 + (ci & 31)] = f2bf(w2[(size_t)i * 9 + k]);
  } else if (id < 260096) {
    int i = id - 204800;
    int o = i / 256, ci = i % 256;
    #pragma unroll
    for (int k = 0; k < 9; ++k)
      wToff[((((size_t)(ci >> 5) * 9 + k) * 216) + o) * 32 + (ci & 31)] = f2bf(woff[(size_t)i * 9 + k]);
  } else if (id < 325632) {
    int i = id - 260096;
    int o = i >> 8, ci = i & 255;
    int g = ci >> 5, cg = ci & 31;
    #pragma unroll
    for (int k = 0; k < 9; ++k)
      wTd[(((size_t)g * 9 + k) * 256 + o) * 32 + cg] = f2bf(wdcn[(size_t)i * 9 + k]);
  } else if (id < 326400) {
    sbuf[id - 325632] = 0.f;
  }
}

// ---- merged input build: y==0 resize inpfeat -> cols [0,32); y>=1 x_main ----
__global__ void k_inT(const float* __restrict__ inpf, const float* __restrict__ xm,
                      short* __restrict__ dst) {
  int t = threadIdx.x;
  int p0 = blockIdx.x * 64;
  int cg = blockIdx.y;                       // 0..8
  int b = blockIdx.z;
  int px = t >> 2, cq = t & 3;
  int p = p0 + px;
  short8 v;
  if (cg == 0) {
    int y = p >> 6, x = p & 63;
    #pragma unroll
    for (int j = 0; j < 8; ++j) {
      int c = cq * 8 + j;
      const float* src = inpf + ((size_t)b * CC + c) * (2 * H) * (2 * W) + (2 * y) * (2 * W) + 2 * x;
      v[j] = f2bf(0.25f * (src[0] + src[1] + src[2 * W] + src[2 * W + 1]));
    }
    *(short8*)(dst + ((size_t)b * HW + p) * 288 + cq * 8) = v;
  } else {
    int cc0 = (cg - 1) * 32;
    const float* s = xm + ((size_t)b * C + cc0 + cq * 8) * HW + p;
    #pragma unroll
    for (int j = 0; j < 8; ++j) v[j] = f2bf(s[(size_t)j * HW]);
    *(short8*)(dst + ((size_t)b * HW + p) * 288 + 32 + cc0 + cq * 8) = v;
  }
}

// ---------------- transpose+convert: fp32 [Csrc][HW] -> bf16 [HW][Cdst] ------
__global__ void k_transpose(const float* __restrict__ src, short* __restrict__ dst,
                            int Csrc, int Cdst, int coff) {
  int t = threadIdx.x;
  int p0 = blockIdx.x * 64;
  int cc0 = blockIdx.y * 32;
  int b = blockIdx.z;
  int px = t >> 2, cq = t & 3;
  const float* s = src + ((size_t)b * Csrc + cc0 + cq * 8) * HW + p0 + px;
  short8 v;
  #pragma unroll
  for (int j = 0; j < 8; ++j) v[j] = f2bf(s[(size_t)j * HW]);
  *(short8*)(dst + ((size_t)b * HW + p0 + px) * Cdst + coff + cc0 + cq * 8) = v;
}

// -------- LDS-free 1x1 MFMA conv; A from [ck][256][32] (contiguous 1KB) ------
template<int CIN, int OUT_BF16>
__global__ __launch_bounds__(256) void k_conv1x1_mfma(
    const short* __restrict__ gT, const short* __restrict__ wT,
    const float* __restrict__ bias, void* __restrict__ outp) {
  const int tid = threadIdx.x;
  const int lane = tid & 63, wv = tid >> 6;
  const int l15 = lane & 15, l4 = lane >> 4;
  const int lin = blockIdx.x + gridDim.x * (blockIdx.y + gridDim.y * blockIdx.z);
  const int nb = gridDim.x * gridDim.y * gridDim.z;   // 512
  const int swz = (lin & 7) * (nb >> 3) + (lin >> 3);
  const int bx = swz % gridDim.x;
  const int rem = swz / gridDim.x;
  const int b = rem / gridDim.y;
  const int o0 = (rem % gridDim.y) * 64;
  const int p0 = bx * 128;

  const short* gTb = gT + (size_t)b * HW * CIN;
  const short* br[2];
  #pragma unroll
  for (int nt = 0; nt < 2; ++nt)
    br[nt] = gTb + (size_t)(p0 + wv * 32 + nt * 16 + l15) * CIN;
  const short* aw = wT + (size_t)(o0 + l15) * 32 + l4 * 8;

  f32x4 acc[4][2];
  #pragma unroll
  for (int mt = 0; mt < 4; ++mt)
    #pragma unroll
    for (int nt = 0; nt < 2; ++nt) acc[mt][nt] = (f32x4)0.f;

  short8 a_c[4], b_c[2], a_n[4], b_n[2];
  #pragma unroll
  for (int mt = 0; mt < 4; ++mt) a_c[mt] = *(const short8*)(aw + mt * (16 * 32));
  #pragma unroll
  for (int nt = 0; nt < 2; ++nt) b_c[nt] = *(const short8*)(br[nt] + l4 * 8);

  for (int ck = 0; ck < CIN / 32; ++ck) {
    if (ck + 1 < CIN / 32) {
      const short* awn = aw + (size_t)(ck + 1) * 256 * 32;
      int cin_n = (ck + 1) * 32 + l4 * 8;
      #pragma unroll
      for (int mt = 0; mt < 4; ++mt) a_n[mt] = *(const short8*)(awn + mt * (16 * 32));
      #pragma unroll
      for (int nt = 0; nt < 2; ++nt) b_n[nt] = *(const short8*)(br[nt] + cin_n);
    }
    #pragma unroll
    for (int mt = 0; mt < 4; ++mt)
      #pragma unroll
      for (int nt = 0; nt < 2; ++nt)
        acc[mt][nt] = __builtin_amdgcn_mfma_f32_16x16x32_bf16(
            a_c[mt], b_c[nt], acc[mt][nt], 0, 0, 0);
    if (ck + 1 < CIN / 32) {
      #pragma unroll
      for (int mt = 0; mt < 4; ++mt) a_c[mt] = a_n[mt];
      #pragma unroll
      for (int nt = 0; nt < 2; ++nt) b_c[nt] = b_n[nt];
    }
  }

  #pragma unroll
  for (int mt = 0; mt < 4; ++mt) {
    #pragma unroll
    for (int nt = 0; nt < 2; ++nt) {
      int p = p0 + wv * 32 + nt * 16 + l15;
      if (OUT_BF16) {
        short4 vv;
        #pragma unroll
        for (int r = 0; r < 4; ++r) {
          int oo = o0 + mt * 16 + l4 * 4 + r;
          ((short*)&vv)[r] = f2bf(acc[mt][nt][r] + bias[oo]);
        }
        *(short4*)((short*)outp + ((size_t)b * HW + p) * 256 + o0 + mt * 16 + l4 * 4) = vv;
      } else {
        float* out = (float*)outp;
        #pragma unroll
        for (int r = 0; r < 4; ++r) {
          int oo = o0 + mt * 16 + l4 * 4 + r;
          out[((size_t)b * 256 + oo) * HW + p] = acc[mt][nt][r] + bias[oo];
        }
      }
    }
  }
}

// ------ MFMA 3x3 conv, 128-px tile (R13 structure), A from [ck][tap][o][32] --
template<int CIN, int COUT>
__global__ __launch_bounds__(256) void k_mfma_conv9(
    const short* __restrict__ gT, const short* __restrict__ wT,
    const float* __restrict__ bias, float* __restrict__ out) {
  constexpr int POS = 4 * 66;
  constexpr int PSTR = 40;                          // u16 per position (80 B)
  constexpr int NCH = (POS * 4 + 255) / 256;        // 5
  __shared__ short lds[POS * PSTR];
  const int tid = threadIdx.x;
  const int lane = tid & 63, wv = tid >> 6;
  const int l15 = lane & 15, l4 = lane >> 4;
  const int lin = blockIdx.x + gridDim.x * (blockIdx.y + gridDim.y * blockIdx.z);
  const int nb = gridDim.x * gridDim.y * gridDim.z;   // 512
  const int swz = (lin & 7) * (nb >> 3) + (lin >> 3);
  const int bx = swz % gridDim.x;
  const int rem = swz / gridDim.x;
  const int b = rem / gridDim.y;
  const int o0 = (rem % gridDim.y) * 64;
  const int p0 = bx * 128;
  const int y0 = p0 >> 6;                           // 2 image rows per block

  f32x4 acc[4][2];
  #pragma unroll
  for (int mt = 0; mt < 4; ++mt)
    #pragma unroll
    for (int nt = 0; nt < 2; ++nt) acc[mt][nt] = (f32x4)0.f;

  const short* gTb = gT + (size_t)b * HW * CIN;
  const short8 z8 = {0, 0, 0, 0, 0, 0, 0, 0};

  short8 pf[NCH];
  auto prefetch = [&](int ck) {
    const int ci0 = ck * 32;
    #pragma unroll
    for (int j = 0; j < NCH; ++j) {
      int i = tid + j * 256;
      if (i < POS * 4) {
        int pos = i >> 2, cq = i & 3;
        short8 v = z8;
        int r = pos / 66;
        int cx = pos - r * 66 - 1;
        int y = y0 - 1 + r;
        if ((unsigned)y < (unsigned)H && (unsigned)cx < (unsigned)W)
          v = *(const short8*)(gTb + (size_t)(y * W + cx) * CIN + ci0 + cq * 8);
        pf[j] = v;
      }
    }
  };

  prefetch(0);
  for (int ck = 0; ck < CIN / 32; ++ck) {
    __syncthreads();
    #pragma unroll
    for (int j = 0; j < NCH; ++j) {
      int i = tid + j * 256;
      if (i < POS * 4) {
        int pos = i >> 2, cq = i & 3;
        *(short8*)(lds + pos * PSTR + cq * 8) = pf[j];
      }
    }
    __syncthreads();
    if (ck + 1 < CIN / 32) prefetch(ck + 1);   // next staging flies under MFMA

    const short* wck = wT + (size_t)ck * 9 * COUT * 32;
    for (int tap = 0; tap < 9; ++tap) {
      const short* wtap = wck + (size_t)tap * COUT * 32;
      short8 a[4];
      #pragma unroll
      for (int mt = 0; mt < 4; ++mt) {
        int o_r = o0 + mt * 16 + l15;
        if (COUT % 64 == 0 || o_r < COUT)
          a[mt] = *(const short8*)(wtap + (size_t)o_r * 32 + l4 * 8);
        else
          a[mt] = z8;
      }
      short8 bb[2];
      #pragma unroll
      for (int nt = 0; nt < 2; ++nt) {
        int dy = tap / 3 - 1, dx = tap % 3 - 1;
        int row = (wv >> 1) + dy + 1;
        int col = (wv & 1) * 32 + nt * 16 + l15 + dx + 1;
        bb[nt] = *(const short8*)(lds + (row * 66 + col) * PSTR + l4 * 8);
      }
      #pragma unroll
      for (int mt = 0; mt < 4; ++mt)
        #pragma unroll
        for (int nt = 0; nt < 2; ++nt)
          acc[mt][nt] = __builtin_amdgcn_mfma_f32_16x16x32_bf16(
              a[mt], bb[nt], acc[mt][nt], 0, 0, 0);
    }
  }

  #pragma unroll
  for (int mt = 0; mt < 4; ++mt) {
    #pragma unroll
    for (int nt = 0; nt < 2; ++nt) {
      int p = p0 + wv * 32 + nt * 16 + l15;
      #pragma unroll
      for (int r = 0; r < 4; ++r) {
        int oo = o0 + mt * 16 + l4 * 4 + r;
        if (COUT % 64 == 0 || oo < COUT)
          out[((size_t)b * COUT + oo) * HW + p] = acc[mt][nt][r] + bias[oo];
      }
    }
  }
}

// -------- partial GN stats: grid (GN,B,4), float4 reads, atomic accumulate ---
__global__ void k_gn_stats_part(const float* __restrict__ in,
                                float* __restrict__ ssum, float* __restrict__ ssq) {
  int g = blockIdx.x, b = blockIdx.y, z = blockIdx.z;
  const float4* base = (const float4*)(in + ((size_t)b * C + g * CPG) * HW) + z * 2048;
  float s = 0.f, s2 = 0.f;
  for (int i = threadIdx.x; i < 2048; i += 256) {
    float4 v = base[i];
    s  += v.x + v.y + v.z + v.w;
    s2 += v.x * v.x + v.y * v.y + v.z * v.z + v.w * v.w;
  }
  #pragma unroll
  for (int off = 32; off > 0; off >>= 1) {
    s  += __shfl_down(s, off);
    s2 += __shfl_down(s2, off);
  }
  __shared__ float sh[8];
  int wid = threadIdx.x >> 6, lane = threadIdx.x & 63;
  if (lane == 0) { sh[wid] = s; sh[4 + wid] = s2; }
  __syncthreads();
  if (threadIdx.x == 0) {
    atomicAdd(&ssum[b * GN + g], sh[0] + sh[1] + sh[2] + sh[3]);
    atomicAdd(&ssq[b * GN + g], sh[4] + sh[5] + sh[6] + sh[7]);
  }
}

// ------- GN apply + SiLU; MODE: 0 = bf16 T only, 1 = T + f32, 2 = f32 only ---
template<int MODE>
__global__ void k_gnt(const float* __restrict__ in,
                      const float* __restrict__ ssum, const float* __restrict__ ssq,
                      const float* __restrict__ gamma, const float* __restrict__ beta,
                      short* __restrict__ T, float* __restrict__ outf) {
  int t = threadIdx.x;
  int p0 = blockIdx.x * 64;
  int b = blockIdx.y;
  int cc0 = blockIdx.z * 64;
  int px = t >> 2, cq = t & 3;
  int p = p0 + px;
  #pragma unroll
  for (int cc = 0; cc < 64; cc += 32) {
    int cbase = cc0 + cc + cq * 8;
    int bg = b * GN + (cbase >> 3);
    float mean = ssum[bg] * (1.f / (CPG * HW));
    float var  = ssq[bg] * (1.f / (CPG * HW)) - mean * mean;
    float inv  = rsqrtf(var + 1e-6f);
    short8 v;
    #pragma unroll
    for (int j = 0; j < 8; ++j) {
      int c = cbase + j;
      float x = in[((size_t)b * C + c) * HW + p];
      float y = (x - mean) * inv * gamma[c] + beta[c];
      y = y / (1.f + expf(-y));
      if (MODE >= 1) outf[((size_t)b * C + c) * HW + p] = y;
      v[j] = f2bf(y);
    }
    if (MODE != 2) *(short8*)(T + ((size_t)b * HW + p) * C + cbase) = v;
  }
}

// ------- depthwise 7x7, pad 3, 4px/thread + fused gn2 partial stats ----------
__global__ void k_dw7(const float* __restrict__ in, const float* __restrict__ w,
                      const float* __restrict__ bias, float* __restrict__ out,
                      float* __restrict__ ssum, float* __restrict__ ssq) {
  int t = blockIdx.x * 256 + threadIdx.x;
  int c = blockIdx.y, b = blockIdx.z;
  int x4 = (t & 15) * 4;
  int y = t >> 4;
  const float* src = in + ((size_t)b * C + c) * HW;
  const float* wk = w + c * 49;
  float bz = bias[c];
  float a0 = bz, a1 = bz, a2 = bz, a3 = bz;
  const float4 z4 = make_float4(0.f, 0.f, 0.f, 0.f);
  #pragma unroll
  for (int ky = 0; ky < 7; ++ky) {
    int yy = y + ky - 3;
    if ((unsigned)yy >= (unsigned)H) continue;
    const float* row = src + yy * W;
    float4 A = (x4 >= 4)  ? *(const float4*)(row + x4 - 4) : z4;
    float4 Bm = *(const float4*)(row + x4);
    float4 Cx = (x4 <= 56) ? *(const float4*)(row + x4 + 4) : z4;
    float rb[12] = {A.x, A.y, A.z, A.w, Bm.x, Bm.y, Bm.z, Bm.w, Cx.x, Cx.y, Cx.z, Cx.w};
    #pragma unroll
    for (int kx = 0; kx < 7; ++kx) {
      float wv = wk[ky * 7 + kx];
      a0 += wv * rb[kx + 1];
      a1 += wv * rb[kx + 2];
      a2 += wv * rb[kx + 3];
      a3 += wv * rb[kx + 4];
    }
  }
  *(float4*)(out + ((size_t)b * C + c) * HW + y * W + x4) = make_float4(a0, a1, a2, a3);
  float s = a0 + a1 + a2 + a3;
  float s2 = a0 * a0 + a1 * a1 + a2 * a2 + a3 * a3;
  #pragma unroll
  for (int off = 32; off > 0; off >>= 1) {
    s  += __shfl_down(s, off);
    s2 += __shfl_down(s2, off);
  }
  __shared__ float sh[8];
  int wid = threadIdx.x >> 6, lane = threadIdx.x & 63;
  if (lane == 0) { sh[wid] = s; sh[4 + wid] = s2; }
  __syncthreads();
  if (threadIdx.x == 0) {
    atomicAdd(&ssum[b * GN + (c >> 3)], sh[0] + sh[1] + sh[2] + sh[3]);
    atomicAdd(&ssq[b * GN + (c >> 3)], sh[4] + sh[5] + sh[6] + sh[7]);
  }
}

// ---- modulated deformable conv 3x3 via MFMA (v13: P/C, 16-px tile) ----------
// Grid 1024 = 4 blocks/CU, 23KB LDS, VGPR 64 -> up to 32 waves/CU resident.
// Waves 0-3 consumers (64 outs x 16 px each), 4-7 producers (fused per-item
// gather+combine, no cross-item liveness).
__global__ __launch_bounds__(512, 4) void k_deform_mfma(
    const short* __restrict__ xmT, const float* __restrict__ co,
    const short* __restrict__ wT, const float* __restrict__ bias,
    float* __restrict__ out) {
  constexpr int PSTR = 40;
  __shared__ short s[2][K * 16 * PSTR];     // 2 x 11520 B
  const int tid = threadIdx.x;
  const int lane = tid & 63, wv = tid >> 6;
  const int l15 = lane & 15, l4 = lane >> 4;
  const int lin = blockIdx.x + gridDim.x * blockIdx.y;
  const int nb = gridDim.x * gridDim.y;     // 1024, %8==0
  const int swz = (lin & 7) * (nb >> 3) + (lin >> 3);
  const int b = swz / (HW / 16);
  const int p0 = (swz % (HW / 16)) * 16;
  const bool producer = (wv >= 4);
  const int o0 = wv * 64;                   // consumer o-tile (wv 0..3)
  const int pid = tid - 256;                // producer thread id (0..255)

  const short* xb = xmT + (size_t)b * HW * C;
  const float* cob = co + (size_t)b * OFFC * HW;

  // staging: 9 taps x 16 px x 4 cq = 576 chunks; 256 threads -> 2 + (pid<64)
  float cdy[3], cdx[3], cml[3];

  auto loadco = [&](int g) {
    #pragma unroll
    for (int j = 0; j < 3; ++j) {
      if (j == 2 && pid >= 64) continue;
      int i = pid + j * 256;
      int tap = i >> 6, pl = (i & 63) >> 2;
      int p = p0 + pl;
      cdy[j] = cob[(size_t)((g * K + tap) * 2) * HW + p];
      cdx[j] = cob[(size_t)((g * K + tap) * 2 + 1) * HW + p];
      cml[j] = cob[(size_t)(144 + g * K + tap) * HW + p];
    }
  };

  auto stage = [&](int g, short* sb) {
    #pragma unroll
    for (int j = 0; j < 3; ++j) {
      if (j == 2 && pid >= 64) continue;
      int i = pid + j * 256;
      int tap = i >> 6, r = i & 63, pl = r >> 2, cq = r & 3;
      int p = p0 + pl;
      float m = 1.f / (1.f + expf(-cml[j]));
      int kh = tap / 3 - 1, kw = tap % 3 - 1;
      int py = p >> 6, px = p & 63;
      float yy = (float)(py + kh) + cdy[j];
      float xx = (float)(px + kw) + cdx[j];
      float yf = floorf(yy), xf = floorf(xx);
      float wy = yy - yf, wx = xx - xf;
      int y0 = (int)yf, x0 = (int)xf;
      bool yv0 = (unsigned)y0 < (unsigned)H, yv1 = (unsigned)(y0 + 1) < (unsigned)H;
      bool xv0 = (unsigned)x0 < (unsigned)W, xv1 = (unsigned)(x0 + 1) < (unsigned)W;
      int yc0 = min(max(y0, 0), H - 1), yc1 = min(max(y0 + 1, 0), H - 1);
      int xc0 = min(max(x0, 0), W - 1), xc1 = min(max(x0 + 1, 0), W - 1);
      float w00 = (yv0 && xv0) ? (1.f - wy) * (1.f - wx) * m : 0.f;
      float w01 = (yv0 && xv1) ? (1.f - wy) * wx * m : 0.f;
      float w10 = (yv1 && xv0) ? wy * (1.f - wx) * m : 0.f;
      float w11 = (yv1 && xv1) ? wy * wx * m : 0.f;
      const short* xg = xb + g * 32 + cq * 8;
      short8 v00 = *(const short8*)(xg + (size_t)(yc0 * W + xc0) * C);
      short8 v01 = *(const short8*)(xg + (size_t)(yc0 * W + xc1) * C);
      short8 v10 = *(const short8*)(xg + (size_t)(yc1 * W + xc0) * C);
      short8 v11 = *(const short8*)(xg + (size_t)(yc1 * W + xc1) * C);
      short8 rr;
      #pragma unroll
      for (int jj = 0; jj < 8; ++jj)
        rr[jj] = f2bf(w00 * bf2f(v00[jj]) + w01 * bf2f(v01[jj]) +
                      w10 * bf2f(v10[jj]) + w11 * bf2f(v11[jj]));
      *(short8*)(sb + (tap * 16 + pl) * PSTR + cq * 8) = rr;
    }
  };

  f32x4 acc[4];
  #pragma unroll
  for (int mt = 0; mt < 4; ++mt) acc[mt] = (f32x4)0.f;

  if (producer) {
    loadco(0);
    stage(0, s[0]);
    loadco(1);
  }
  __syncthreads();
  for (int g = 0; g < G; ++g) {
    if (producer) {
      if (g < G - 1) {
        stage(g + 1, s[(g + 1) & 1]);
        if (g < G - 2) loadco(g + 2);
      }
    } else {
      const short* sb = s[g & 1];
      const short* wg = wT + (size_t)g * K * 256 * 32;
      short8 a_c[4], a_n[4];
      #pragma unroll
      for (int mt = 0; mt < 4; ++mt)
        a_c[mt] = *(const short8*)(wg + (size_t)(o0 + mt * 16 + l15) * 32 + l4 * 8);
      for (int k = 0; k < K; ++k) {
        short8 bb = *(const short8*)(sb + (k * 16 + l15) * PSTR + l4 * 8);
        if (k < K - 1) {
          #pragma unroll
          for (int mt = 0; mt < 4; ++mt)
            a_n[mt] = *(const short8*)(wg + (size_t)((k + 1) * 256 + o0 + mt * 16 + l15) * 32 + l4 * 8);
        }
        #pragma unroll
        for (int mt = 0; mt < 4; ++mt)
          acc[mt] = __builtin_amdgcn_mfma_f32_16x16x32_bf16(a_c[mt], bb, acc[mt], 0, 0, 0);
        if (k < K - 1) {
          #pragma unroll
          for (int mt = 0; mt < 4; ++mt) a_c[mt] = a_n[mt];
        }
      }
    }
    __syncthreads();
  }

  if (!producer) {
    const int p = p0 + l15;
    #pragma unroll
    for (int mt = 0; mt < 4; ++mt) {
      #pragma unroll
      for (int r = 0; r < 4; ++r) {
        int oo = o0 + mt * 16 + l4 * 4 + r;
        out[((size_t)b * C + oo) * HW + p] = acc[mt][r] + bias[oo];
      }
    }
  }
}

extern "C" void kernel_launch(void* const* d_in, const int* in_sizes, int n_in,
                              void* d_out, int out_size, void* d_ws, size_t ws_size,
                              hipStream_t stream) {
  const float* x_main  = (const float*)d_in[0];
  const float* inpfeat = (const float*)d_in[1];
  const float* w1a = (const float*)d_in[2];
  const float* b1a = (const float*)d_in[3];
  const float* g1  = (const float*)d_in[4];
  const float* be1 = (const float*)d_in[5];
  const float* w1b = (const float*)d_in[6];
  const float* b1b = (const float*)d_in[7];
  const float* g2  = (const float*)d_in[8];
  const float* be2 = (const float*)d_in[9];
  const float* w1c = (const float*)d_in[10];
  const float* b1c = (const float*)d_in[11];
  const float* w2  = (const float*)d_in[12];
  const float* b2  = (const float*)d_in[13];
  const float* g3  = (const float*)d_in[14];
  const float* be3 = (const float*)d_in[15];
  const float* w_off = (const float*)d_in[16];
  const float* b_off = (const float*)d_in[17];
  const float* w_dcn = (const float*)d_in[18];
  const float* b_dcn = (const float*)d_in[19];

  float* warp_out = (float*)d_out;                      // output 0 [B,C,H,W]
  float* off_out  = warp_out + (size_t)B * C * HW;      // output 1 [B,C,H,W]

  // ---- workspace carve (bytes) ----
  char* ws = (char*)d_ws;
  float* r_inp = (float*)ws;                            //  2 MB; wTd home
  float* fA    = (float*)(ws + (2u << 20));             // 16 MB [B][C][HW] (also co, Tc)
  short* T288  = (short*)(ws + (2u << 20) + (16u << 20));   // 9.44 MB [B][HW][288]
  char*  wbase = ws + (2u << 20) + (16u << 20) + 9437184;
  short* wT1a  = (short*)(wbase);                       // 147456 B
  short* wT1c  = (short*)(wbase + 147456);              // 131072 B
  short* wT2   = (short*)(wbase + 147456 + 131072);     // 1179648 B
  short* wToff = (short*)(wbase + 147456 + 131072 + 1179648);  // 995328 B
  float* sbuf  = (float*)(wbase + 147456 + 131072 + 1179648 + 995328);  // 768 floats
  float* ssum1 = sbuf,       *ssq1 = sbuf + 128;
  float* ssum2 = sbuf + 256, *ssq2 = sbuf + 384;
  float* ssum3 = sbuf + 512, *ssq3 = sbuf + 640;
  short* wTd   = (short*)r_inp;                         // [g][tap][o][32]
  short* Tc    = (short*)fA;                            // conv1c bf16 out [B][HW][256]
  short* T2    = T288;                                  // gn2/gn3 bf16 out
  float* fB = warp_out;   // scratch until final deform write
  float* co = fA;

  k_prep<<<dim3(1275), 256, 0, stream>>>(w1a, wT1a, w1c, wT1c, w2, wT2,
                                         w_off, wToff, w_dcn, wTd, sbuf);
  // merged resize + x_main transpose into T288
  k_inT<<<dim3(HW / 64, 9, B), 256, 0, stream>>>(inpfeat, x_main, T288);
  k_conv1x1_mfma<288, 0><<<dim3(HW / 128, 4, B), 256, 0, stream>>>(T288, wT1a, b1a, fA);
  // gn1: partial stats + f32-only apply (in-place on fA)
  k_gn_stats_part<<<dim3(GN, B, 4), 256, 0, stream>>>(fA, ssum1, ssq1);
  k_gnt<2><<<dim3(HW / 64, B, 4), 256, 0, stream>>>(fA, ssum1, ssq1, g1, be1, nullptr, fA);
  // dw7 (+ fused gn2 partial stats)
  k_dw7<<<dim3(HW / 1024, C, B), 256, 0, stream>>>(fA, w1b, b1b, fB, ssum2, ssq2);
  k_gnt<0><<<dim3(HW / 64, B, 4), 256, 0, stream>>>(fB, ssum2, ssq2, g2, be2, T2, nullptr);
  // conv1c: bf16 transposed output straight into Tc
  k_conv1x1_mfma<256, 1><<<dim3(HW / 128, 4, B), 256, 0, stream>>>(T2, wT1c, b1c, Tc);
  k_mfma_conv9<256, 256><<<dim3(HW / 128, 4, B), 256, 0, stream>>>(Tc, wT2, b2, fB);
  // gn3: partial stats + (T2 + f32 off_out)
  k_gn_stats_part<<<dim3(GN, B, 4), 256, 0, stream>>>(fB, ssum3, ssq3);
  k_gnt<1><<<dim3(HW / 64, B, 4), 256, 0, stream>>>(fB, ssum3, ssq3, g3, be3, T2, off_out);
  k_mfma_conv9<256, 216><<<dim3(HW / 128, 4, B), 256, 0, stream>>>(T2, wToff, b_off, co);
  // T288 dead -> reuse as xmT [B][HW][256] bf16
  k_transpose<<<dim3(HW / 64, 8, B), 256, 0, stream>>>(x_main, T288, C, 256, 0);
  k_deform_mfma<<<dim3(HW / 16, B), 512, 0, stream>>>(T288, co, wTd, b_dcn, warp_out);
}

// Round 23
// 287.117 us; speedup vs baseline: 1.0914x; 1.0914x over previous
//
#include <hip/hip_runtime.h>
#include <math.h>

constexpr int B = 4, C = 256, CC = 32, H = 64, W = 64, HW = H * W;
constexpr int G = 8, K = 9, GN = 32, CPG = C / GN;   // CPG = 8
constexpr int OFFC = 3 * G * K;                       // 216

typedef __attribute__((ext_vector_type(8))) short short8;
typedef __attribute__((ext_vector_type(4))) float f32x4;

__device__ inline short f2bf(float f) {
  unsigned u = __builtin_bit_cast(unsigned, f);
  return (short)((u + 0x7FFFu + ((u >> 16) & 1u)) >> 16);
}
__device__ inline float bf2f(short s) {
  unsigned u = ((unsigned)(unsigned short)s) << 16;
  return __builtin_bit_cast(float, u);
}

// ---------------- merged prep: weight transforms (K-block-major) + zero ------
__global__ void k_prep(const float* __restrict__ w1a, short* __restrict__ wT1a,
                       const float* __restrict__ w1c, short* __restrict__ wT1c,
                       const float* __restrict__ w2, short* __restrict__ wT2,
                       const float* __restrict__ woff, short* __restrict__ wToff,
                       const float* __restrict__ wdcn, short* __restrict__ wTd,
                       float* __restrict__ sbuf) {
  int id = blockIdx.x * 256 + threadIdx.x;
  if (id < 73728) {
    int o = id / 288, ci = id % 288;
    wT1a[(((size_t)(ci >> 5) * 256) + o) * 32 + (ci & 31)] = f2bf(w1a[id]);
  } else if (id < 139264) {
    int i = id - 73728;
    int o = i >> 8, ci = i & 255;
    wT1c[(((size_t)(ci >> 5) * 256) + o) * 32 + (ci & 31)] = f2bf(w1c[i]);
  } else if (id < 204800) {
    int i = id - 139264;
    int o = i >> 8, ci = i & 255;
    #pragma unroll
    for (int k = 0; k < 9; ++k)
      wT2[((((size_t)(ci >> 5) * 9 + k) * 256) + o) * 32 + (ci & 31)] = f2bf(w2[(size_t)i * 9 + k]);
  } else if (id < 260096) {
    int i = id - 204800;
    int o = i / 256, ci = i % 256;
    #pragma unroll
    for (int k = 0; k < 9; ++k)
      wToff[((((size_t)(ci >> 5) * 9 + k) * 216) + o) * 32 + (ci & 31)] = f2bf(woff[(size_t)i * 9 + k]);
  } else if (id < 325632) {
    int i = id - 260096;
    int o = i >> 8, ci = i & 255;
    int g = ci >> 5, cg = ci & 31;
    #pragma unroll
    for (int k = 0; k < 9; ++k)
      wTd[(((size_t)g * 9 + k) * 256 + o) * 32 + cg] = f2bf(wdcn[(size_t)i * 9 + k]);
  } else if (id < 326400) {
    sbuf[id - 325632] = 0.f;
  }
}

// ---- merged input build: y==0 resize inpfeat -> cols [0,32); y>=1 x_main ----
__global__ void k_inT(const float* __restrict__ inpf, const float* __restrict__ xm,
                      short* __restrict__ dst) {
  int t = threadIdx.x;
  int p0 = blockIdx.x * 64;
  int cg = blockIdx.y;                       // 0..8
  int b = blockIdx.z;
  int px = t >> 2, cq = t & 3;
  int p = p0 + px;
  short8 v;
  if (cg == 0) {
    int y = p >> 6, x = p & 63;
    #pragma unroll
    for (int j = 0; j < 8; ++j) {
      int c = cq * 8 + j;
      const float* src = inpf + ((size_t)b * CC + c) * (2 * H) * (2 * W) + (2 * y) * (2 * W) + 2 * x;
      v[j] = f2bf(0.25f * (src[0] + src[1] + src[2 * W] + src[2 * W + 1]));
    }
    *(short8*)(dst + ((size_t)b * HW + p) * 288 + cq * 8) = v;
  } else {
    int cc0 = (cg - 1) * 32;
    const float* s = xm + ((size_t)b * C + cc0 + cq * 8) * HW + p;
    #pragma unroll
    for (int j = 0; j < 8; ++j) v[j] = f2bf(s[(size_t)j * HW]);
    *(short8*)(dst + ((size_t)b * HW + p) * 288 + 32 + cc0 + cq * 8) = v;
  }
}

// ---------------- transpose+convert: fp32 [Csrc][HW] -> bf16 [HW][Cdst] ------
__global__ void k_transpose(const float* __restrict__ src, short* __restrict__ dst,
                            int Csrc, int Cdst, int coff) {
  int t = threadIdx.x;
  int p0 = blockIdx.x * 64;
  int cc0 = blockIdx.y * 32;
  int b = blockIdx.z;
  int px = t >> 2, cq = t & 3;
  const float* s = src + ((size_t)b * Csrc + cc0 + cq * 8) * HW + p0 + px;
  short8 v;
  #pragma unroll
  for (int j = 0; j < 8; ++j) v[j] = f2bf(s[(size_t)j * HW]);
  *(short8*)(dst + ((size_t)b * HW + p0 + px) * Cdst + coff + cc0 + cq * 8) = v;
}

// -------- LDS-free 1x1 MFMA conv; A from [ck][256][32] (contiguous 1KB) ------
template<int CIN, int OUT_BF16>
__global__ __launch_bounds__(256) void k_conv1x1_mfma(
    const short* __restrict__ gT, const short* __restrict__ wT,
    const float* __restrict__ bias, void* __restrict__ outp) {
  const int tid = threadIdx.x;
  const int lane = tid & 63, wv = tid >> 6;
  const int l15 = lane & 15, l4 = lane >> 4;
  const int lin = blockIdx.x + gridDim.x * (blockIdx.y + gridDim.y * blockIdx.z);
  const int nb = gridDim.x * gridDim.y * gridDim.z;   // 512
  const int swz = (lin & 7) * (nb >> 3) + (lin >> 3);
  const int bx = swz % gridDim.x;
  const int rem = swz / gridDim.x;
  const int b = rem / gridDim.y;
  const int o0 = (rem % gridDim.y) * 64;
  const int p0 = bx * 128;

  const short* gTb = gT + (size_t)b * HW * CIN;
  const short* br[2];
  #pragma unroll
  for (int nt = 0; nt < 2; ++nt)
    br[nt] = gTb + (size_t)(p0 + wv * 32 + nt * 16 + l15) * CIN;
  const short* aw = wT + (size_t)(o0 + l15) * 32 + l4 * 8;

  f32x4 acc[4][2];
  #pragma unroll
  for (int mt = 0; mt < 4; ++mt)
    #pragma unroll
    for (int nt = 0; nt < 2; ++nt) acc[mt][nt] = (f32x4)0.f;

  short8 a_c[4], b_c[2], a_n[4], b_n[2];
  #pragma unroll
  for (int mt = 0; mt < 4; ++mt) a_c[mt] = *(const short8*)(aw + mt * (16 * 32));
  #pragma unroll
  for (int nt = 0; nt < 2; ++nt) b_c[nt] = *(const short8*)(br[nt] + l4 * 8);

  for (int ck = 0; ck < CIN / 32; ++ck) {
    if (ck + 1 < CIN / 32) {
      const short* awn = aw + (size_t)(ck + 1) * 256 * 32;
      int cin_n = (ck + 1) * 32 + l4 * 8;
      #pragma unroll
      for (int mt = 0; mt < 4; ++mt) a_n[mt] = *(const short8*)(awn + mt * (16 * 32));
      #pragma unroll
      for (int nt = 0; nt < 2; ++nt) b_n[nt] = *(const short8*)(br[nt] + cin_n);
    }
    #pragma unroll
    for (int mt = 0; mt < 4; ++mt)
      #pragma unroll
      for (int nt = 0; nt < 2; ++nt)
        acc[mt][nt] = __builtin_amdgcn_mfma_f32_16x16x32_bf16(
            a_c[mt], b_c[nt], acc[mt][nt], 0, 0, 0);
    if (ck + 1 < CIN / 32) {
      #pragma unroll
      for (int mt = 0; mt < 4; ++mt) a_c[mt] = a_n[mt];
      #pragma unroll
      for (int nt = 0; nt < 2; ++nt) b_c[nt] = b_n[nt];
    }
  }

  #pragma unroll
  for (int mt = 0; mt < 4; ++mt) {
    #pragma unroll
    for (int nt = 0; nt < 2; ++nt) {
      int p = p0 + wv * 32 + nt * 16 + l15;
      if (OUT_BF16) {
        short4 vv;
        #pragma unroll
        for (int r = 0; r < 4; ++r) {
          int oo = o0 + mt * 16 + l4 * 4 + r;
          ((short*)&vv)[r] = f2bf(acc[mt][nt][r] + bias[oo]);
        }
        *(short4*)((short*)outp + ((size_t)b * HW + p) * 256 + o0 + mt * 16 + l4 * 4) = vv;
      } else {
        float* out = (float*)outp;
        #pragma unroll
        for (int r = 0; r < 4; ++r) {
          int oo = o0 + mt * 16 + l4 * 4 + r;
          out[((size_t)b * 256 + oo) * HW + p] = acc[mt][nt][r] + bias[oo];
        }
      }
    }
  }
}

// ------ MFMA 3x3 conv, 128-px tile (R13 structure), A from [ck][tap][o][32] --
template<int CIN, int COUT>
__global__ __launch_bounds__(256) void k_mfma_conv9(
    const short* __restrict__ gT, const short* __restrict__ wT,
    const float* __restrict__ bias, float* __restrict__ out) {
  constexpr int POS = 4 * 66;
  constexpr int PSTR = 40;                          // u16 per position (80 B)
  constexpr int NCH = (POS * 4 + 255) / 256;        // 5
  __shared__ short lds[POS * PSTR];
  const int tid = threadIdx.x;
  const int lane = tid & 63, wv = tid >> 6;
  const int l15 = lane & 15, l4 = lane >> 4;
  const int lin = blockIdx.x + gridDim.x * (blockIdx.y + gridDim.y * blockIdx.z);
  const int nb = gridDim.x * gridDim.y * gridDim.z;   // 512
  const int swz = (lin & 7) * (nb >> 3) + (lin >> 3);
  const int bx = swz % gridDim.x;
  const int rem = swz / gridDim.x;
  const int b = rem / gridDim.y;
  const int o0 = (rem % gridDim.y) * 64;
  const int p0 = bx * 128;
  const int y0 = p0 >> 6;                           // 2 image rows per block

  f32x4 acc[4][2];
  #pragma unroll
  for (int mt = 0; mt < 4; ++mt)
    #pragma unroll
    for (int nt = 0; nt < 2; ++nt) acc[mt][nt] = (f32x4)0.f;

  const short* gTb = gT + (size_t)b * HW * CIN;
  const short8 z8 = {0, 0, 0, 0, 0, 0, 0, 0};

  short8 pf[NCH];
  auto prefetch = [&](int ck) {
    const int ci0 = ck * 32;
    #pragma unroll
    for (int j = 0; j < NCH; ++j) {
      int i = tid + j * 256;
      if (i < POS * 4) {
        int pos = i >> 2, cq = i & 3;
        short8 v = z8;
        int r = pos / 66;
        int cx = pos - r * 66 - 1;
        int y = y0 - 1 + r;
        if ((unsigned)y < (unsigned)H && (unsigned)cx < (unsigned)W)
          v = *(const short8*)(gTb + (size_t)(y * W + cx) * CIN + ci0 + cq * 8);
        pf[j] = v;
      }
    }
  };

  prefetch(0);
  for (int ck = 0; ck < CIN / 32; ++ck) {
    __syncthreads();
    #pragma unroll
    for (int j = 0; j < NCH; ++j) {
      int i = tid + j * 256;
      if (i < POS * 4) {
        int pos = i >> 2, cq = i & 3;
        *(short8*)(lds + pos * PSTR + cq * 8) = pf[j];
      }
    }
    __syncthreads();
    if (ck + 1 < CIN / 32) prefetch(ck + 1);   // next staging flies under MFMA

    const short* wck = wT + (size_t)ck * 9 * COUT * 32;
    for (int tap = 0; tap < 9; ++tap) {
      const short* wtap = wck + (size_t)tap * COUT * 32;
      short8 a[4];
      #pragma unroll
      for (int mt = 0; mt < 4; ++mt) {
        int o_r = o0 + mt * 16 + l15;
        if (COUT % 64 == 0 || o_r < COUT)
          a[mt] = *(const short8*)(wtap + (size_t)o_r * 32 + l4 * 8);
        else
          a[mt] = z8;
      }
      short8 bb[2];
      #pragma unroll
      for (int nt = 0; nt < 2; ++nt) {
        int dy = tap / 3 - 1, dx = tap % 3 - 1;
        int row = (wv >> 1) + dy + 1;
        int col = (wv & 1) * 32 + nt * 16 + l15 + dx + 1;
        bb[nt] = *(const short8*)(lds + (row * 66 + col) * PSTR + l4 * 8);
      }
      #pragma unroll
      for (int mt = 0; mt < 4; ++mt)
        #pragma unroll
        for (int nt = 0; nt < 2; ++nt)
          acc[mt][nt] = __builtin_amdgcn_mfma_f32_16x16x32_bf16(
              a[mt], bb[nt], acc[mt][nt], 0, 0, 0);
    }
  }

  #pragma unroll
  for (int mt = 0; mt < 4; ++mt) {
    #pragma unroll
    for (int nt = 0; nt < 2; ++nt) {
      int p = p0 + wv * 32 + nt * 16 + l15;
      #pragma unroll
      for (int r = 0; r < 4; ++r) {
        int oo = o0 + mt * 16 + l4 * 4 + r;
        if (COUT % 64 == 0 || oo < COUT)
          out[((size_t)b * COUT + oo) * HW + p] = acc[mt][nt][r] + bias[oo];
      }
    }
  }
}

// -------- partial GN stats: grid (GN,B,4), float4 reads, atomic accumulate ---
__global__ void k_gn_stats_part(const float* __restrict__ in,
                                float* __restrict__ ssum, float* __restrict__ ssq) {
  int g = blockIdx.x, b = blockIdx.y, z = blockIdx.z;
  const float4* base = (const float4*)(in + ((size_t)b * C + g * CPG) * HW) + z * 2048;
  float s = 0.f, s2 = 0.f;
  for (int i = threadIdx.x; i < 2048; i += 256) {
    float4 v = base[i];
    s  += v.x + v.y + v.z + v.w;
    s2 += v.x * v.x + v.y * v.y + v.z * v.z + v.w * v.w;
  }
  #pragma unroll
  for (int off = 32; off > 0; off >>= 1) {
    s  += __shfl_down(s, off);
    s2 += __shfl_down(s2, off);
  }
  __shared__ float sh[8];
  int wid = threadIdx.x >> 6, lane = threadIdx.x & 63;
  if (lane == 0) { sh[wid] = s; sh[4 + wid] = s2; }
  __syncthreads();
  if (threadIdx.x == 0) {
    atomicAdd(&ssum[b * GN + g], sh[0] + sh[1] + sh[2] + sh[3]);
    atomicAdd(&ssq[b * GN + g], sh[4] + sh[5] + sh[6] + sh[7]);
  }
}

// ------- GN apply + SiLU; MODE: 0 = bf16 T only, 1 = T + f32, 2 = f32 only ---
template<int MODE>
__global__ void k_gnt(const float* __restrict__ in,
                      const float* __restrict__ ssum, const float* __restrict__ ssq,
                      const float* __restrict__ gamma, const float* __restrict__ beta,
                      short* __restrict__ T, float* __restrict__ outf) {
  int t = threadIdx.x;
  int p0 = blockIdx.x * 64;
  int b = blockIdx.y;
  int cc0 = blockIdx.z * 64;
  int px = t >> 2, cq = t & 3;
  int p = p0 + px;
  #pragma unroll
  for (int cc = 0; cc < 64; cc += 32) {
    int cbase = cc0 + cc + cq * 8;
    int bg = b * GN + (cbase >> 3);
    float mean = ssum[bg] * (1.f / (CPG * HW));
    float var  = ssq[bg] * (1.f / (CPG * HW)) - mean * mean;
    float inv  = rsqrtf(var + 1e-6f);
    short8 v;
    #pragma unroll
    for (int j = 0; j < 8; ++j) {
      int c = cbase + j;
      float x = in[((size_t)b * C + c) * HW + p];
      float y = (x - mean) * inv * gamma[c] + beta[c];
      y = y / (1.f + expf(-y));
      if (MODE >= 1) outf[((size_t)b * C + c) * HW + p] = y;
      v[j] = f2bf(y);
    }
    if (MODE != 2) *(short8*)(T + ((size_t)b * HW + p) * C + cbase) = v;
  }
}

// ------- depthwise 7x7, pad 3, 4px/thread + fused gn2 partial stats ----------
__global__ void k_dw7(const float* __restrict__ in, const float* __restrict__ w,
                      const float* __restrict__ bias, float* __restrict__ out,
                      float* __restrict__ ssum, float* __restrict__ ssq) {
  int t = blockIdx.x * 256 + threadIdx.x;
  int c = blockIdx.y, b = blockIdx.z;
  int x4 = (t & 15) * 4;
  int y = t >> 4;
  const float* src = in + ((size_t)b * C + c) * HW;
  const float* wk = w + c * 49;
  float bz = bias[c];
  float a0 = bz, a1 = bz, a2 = bz, a3 = bz;
  const float4 z4 = make_float4(0.f, 0.f, 0.f, 0.f);
  #pragma unroll
  for (int ky = 0; ky < 7; ++ky) {
    int yy = y + ky - 3;
    if ((unsigned)yy >= (unsigned)H) continue;
    const float* row = src + yy * W;
    float4 A = (x4 >= 4)  ? *(const float4*)(row + x4 - 4) : z4;
    float4 Bm = *(const float4*)(row + x4);
    float4 Cx = (x4 <= 56) ? *(const float4*)(row + x4 + 4) : z4;
    float rb[12] = {A.x, A.y, A.z, A.w, Bm.x, Bm.y, Bm.z, Bm.w, Cx.x, Cx.y, Cx.z, Cx.w};
    #pragma unroll
    for (int kx = 0; kx < 7; ++kx) {
      float wv = wk[ky * 7 + kx];
      a0 += wv * rb[kx + 1];
      a1 += wv * rb[kx + 2];
      a2 += wv * rb[kx + 3];
      a3 += wv * rb[kx + 4];
    }
  }
  *(float4*)(out + ((size_t)b * C + c) * HW + y * W + x4) = make_float4(a0, a1, a2, a3);
  float s = a0 + a1 + a2 + a3;
  float s2 = a0 * a0 + a1 * a1 + a2 * a2 + a3 * a3;
  #pragma unroll
  for (int off = 32; off > 0; off >>= 1) {
    s  += __shfl_down(s, off);
    s2 += __shfl_down(s2, off);
  }
  __shared__ float sh[8];
  int wid = threadIdx.x >> 6, lane = threadIdx.x & 63;
  if (lane == 0) { sh[wid] = s; sh[4 + wid] = s2; }
  __syncthreads();
  if (threadIdx.x == 0) {
    atomicAdd(&ssum[b * GN + (c >> 3)], sh[0] + sh[1] + sh[2] + sh[3]);
    atomicAdd(&ssq[b * GN + (c >> 3)], sh[4] + sh[5] + sh[6] + sh[7]);
  }
}

// ---------- modulated deformable conv 3x3 via MFMA (v11: producer/consumer) --
// R21-proven form (59us): 32-px tile, grid 512, fused per-item gather+combine.
__global__ __launch_bounds__(512, 4) void k_deform_mfma(
    const short* __restrict__ xmT, const float* __restrict__ co,
    const short* __restrict__ wT, const float* __restrict__ bias,
    float* __restrict__ out) {
  constexpr int PSTR = 40;
  __shared__ short s[2][K * 32 * PSTR];     // 2 x 23040 B
  const int tid = threadIdx.x;
  const int lane = tid & 63, wv = tid >> 6;
  const int l15 = lane & 15, l4 = lane >> 4;
  const int lin = blockIdx.x + gridDim.x * blockIdx.y;
  const int nb = gridDim.x * gridDim.y;     // 512, %8==0
  const int swz = (lin & 7) * (nb >> 3) + (lin >> 3);
  const int b = swz / (HW / 32);
  const int p0 = (swz % (HW / 32)) * 32;
  const bool producer = (wv >= 4);
  const int o0 = wv * 64;                   // consumer o-tile (wv 0..3)
  const int pid = tid - 256;                // producer thread id (0..255)

  const short* xb = xmT + (size_t)b * HW * C;
  const float* cob = co + (size_t)b * OFFC * HW;

  float cdy[5], cdx[5], cml[5];

  auto loadco = [&](int g) {
    #pragma unroll
    for (int j = 0; j < 5; ++j) {
      if (j == 4 && pid >= 128) continue;
      int i = pid + j * 256;
      int tap = i >> 7, pl = (i & 127) >> 2;
      int p = p0 + pl;
      cdy[j] = cob[(size_t)((g * K + tap) * 2) * HW + p];
      cdx[j] = cob[(size_t)((g * K + tap) * 2 + 1) * HW + p];
      cml[j] = cob[(size_t)(144 + g * K + tap) * HW + p];
    }
  };

  auto stage = [&](int g, short* sb) {
    #pragma unroll
    for (int j = 0; j < 5; ++j) {
      if (j == 4 && pid >= 128) continue;
      int i = pid + j * 256;
      int tap = i >> 7, r = i & 127, pl = r >> 2, cq = r & 3;
      int p = p0 + pl;
      float m = 1.f / (1.f + expf(-cml[j]));
      int kh = tap / 3 - 1, kw = tap % 3 - 1;
      int py = p >> 6, px = p & 63;
      float yy = (float)(py + kh) + cdy[j];
      float xx = (float)(px + kw) + cdx[j];
      float yf = floorf(yy), xf = floorf(xx);
      float wy = yy - yf, wx = xx - xf;
      int y0 = (int)yf, x0 = (int)xf;
      bool yv0 = (unsigned)y0 < (unsigned)H, yv1 = (unsigned)(y0 + 1) < (unsigned)H;
      bool xv0 = (unsigned)x0 < (unsigned)W, xv1 = (unsigned)(x0 + 1) < (unsigned)W;
      int yc0 = min(max(y0, 0), H - 1), yc1 = min(max(y0 + 1, 0), H - 1);
      int xc0 = min(max(x0, 0), W - 1), xc1 = min(max(x0 + 1, 0), W - 1);
      float w00 = (yv0 && xv0) ? (1.f - wy) * (1.f - wx) * m : 0.f;
      float w01 = (yv0 && xv1) ? (1.f - wy) * wx * m : 0.f;
      float w10 = (yv1 && xv0) ? wy * (1.f - wx) * m : 0.f;
      float w11 = (yv1 && xv1) ? wy * wx * m : 0.f;
      const short* xg = xb + g * 32 + cq * 8;
      short8 v00 = *(const short8*)(xg + (size_t)(yc0 * W + xc0) * C);
      short8 v01 = *(const short8*)(xg + (size_t)(yc0 * W + xc1) * C);
      short8 v10 = *(const short8*)(xg + (size_t)(yc1 * W + xc0) * C);
      short8 v11 = *(const short8*)(xg + (size_t)(yc1 * W + xc1) * C);
      short8 rr;
      #pragma unroll
      for (int jj = 0; jj < 8; ++jj)
        rr[jj] = f2bf(w00 * bf2f(v00[jj]) + w01 * bf2f(v01[jj]) +
                      w10 * bf2f(v10[jj]) + w11 * bf2f(v11[jj]));
      *(short8*)(sb + (tap * 32 + pl) * PSTR + cq * 8) = rr;
    }
  };

  f32x4 acc[4][2];
  #pragma unroll
  for (int mt = 0; mt < 4; ++mt)
    #pragma unroll
    for (int nt = 0; nt < 2; ++nt) acc[mt][nt] = (f32x4)0.f;

  if (producer) {
    loadco(0);
    stage(0, s[0]);
    loadco(1);
  }
  __syncthreads();
  for (int g = 0; g < G; ++g) {
    if (producer) {
      if (g < G - 1) {
        stage(g + 1, s[(g + 1) & 1]);
        if (g < G - 2) loadco(g + 2);
      }
    } else {
      const short* sb = s[g & 1];
      const short* wg = wT + (size_t)g * K * 256 * 32;
      short8 a_c[4], a_n[4];
      #pragma unroll
      for (int mt = 0; mt < 4; ++mt)
        a_c[mt] = *(const short8*)(wg + (size_t)(o0 + mt * 16 + l15) * 32 + l4 * 8);
      for (int k = 0; k < K; ++k) {
        short8 bb0 = *(const short8*)(sb + (k * 32 + l15) * PSTR + l4 * 8);
        short8 bb1 = *(const short8*)(sb + (k * 32 + 16 + l15) * PSTR + l4 * 8);
        if (k < K - 1) {
          #pragma unroll
          for (int mt = 0; mt < 4; ++mt)
            a_n[mt] = *(const short8*)(wg + (size_t)((k + 1) * 256 + o0 + mt * 16 + l15) * 32 + l4 * 8);
        }
        #pragma unroll
        for (int mt = 0; mt < 4; ++mt) {
          acc[mt][0] = __builtin_amdgcn_mfma_f32_16x16x32_bf16(a_c[mt], bb0, acc[mt][0], 0, 0, 0);
          acc[mt][1] = __builtin_amdgcn_mfma_f32_16x16x32_bf16(a_c[mt], bb1, acc[mt][1], 0, 0, 0);
        }
        if (k < K - 1) {
          #pragma unroll
          for (int mt = 0; mt < 4; ++mt) a_c[mt] = a_n[mt];
        }
      }
    }
    __syncthreads();
  }

  if (!producer) {
    #pragma unroll
    for (int mt = 0; mt < 4; ++mt) {
      #pragma unroll
      for (int nt = 0; nt < 2; ++nt) {
        int p = p0 + nt * 16 + l15;
        #pragma unroll
        for (int r = 0; r < 4; ++r) {
          int oo = o0 + mt * 16 + l4 * 4 + r;
          out[((size_t)b * C + oo) * HW + p] = acc[mt][nt][r] + bias[oo];
        }
      }
    }
  }
}

extern "C" void kernel_launch(void* const* d_in, const int* in_sizes, int n_in,
                              void* d_out, int out_size, void* d_ws, size_t ws_size,
                              hipStream_t stream) {
  const float* x_main  = (const float*)d_in[0];
  const float* inpfeat = (const float*)d_in[1];
  const float* w1a = (const float*)d_in[2];
  const float* b1a = (const float*)d_in[3];
  const float* g1  = (const float*)d_in[4];
  const float* be1 = (const float*)d_in[5];
  const float* w1b = (const float*)d_in[6];
  const float* b1b = (const float*)d_in[7];
  const float* g2  = (const float*)d_in[8];
  const float* be2 = (const float*)d_in[9];
  const float* w1c = (const float*)d_in[10];
  const float* b1c = (const float*)d_in[11];
  const float* w2  = (const float*)d_in[12];
  const float* b2  = (const float*)d_in[13];
  const float* g3  = (const float*)d_in[14];
  const float* be3 = (const float*)d_in[15];
  const float* w_off = (const float*)d_in[16];
  const float* b_off = (const float*)d_in[17];
  const float* w_dcn = (const float*)d_in[18];
  const float* b_dcn = (const float*)d_in[19];

  float* warp_out = (float*)d_out;                      // output 0 [B,C,H,W]
  float* off_out  = warp_out + (size_t)B * C * HW;      // output 1 [B,C,H,W]

  // ---- workspace carve (bytes) ----
  char* ws = (char*)d_ws;
  float* r_inp = (float*)ws;                            //  2 MB; wTd home
  float* fA    = (float*)(ws + (2u << 20));             // 16 MB [B][C][HW] (also co, Tc)
  short* T288  = (short*)(ws + (2u << 20) + (16u << 20));   // 9.44 MB [B][HW][288]
  char*  wbase = ws + (2u << 20) + (16u << 20) + 9437184;
  short* wT1a  = (short*)(wbase);                       // 147456 B
  short* wT1c  = (short*)(wbase + 147456);              // 131072 B
  short* wT2   = (short*)(wbase + 147456 + 131072);     // 1179648 B
  short* wToff = (short*)(wbase + 147456 + 131072 + 1179648);  // 995328 B
  float* sbuf  = (float*)(wbase + 147456 + 131072 + 1179648 + 995328);  // 768 floats
  float* ssum1 = sbuf,       *ssq1 = sbuf + 128;
  float* ssum2 = sbuf + 256, *ssq2 = sbuf + 384;
  float* ssum3 = sbuf + 512, *ssq3 = sbuf + 640;
  short* wTd   = (short*)r_inp;                         // [g][tap][o][32]
  short* Tc    = (short*)fA;                            // conv1c bf16 out [B][HW][256]
  short* T2    = T288;                                  // gn2/gn3 bf16 out
  float* fB = warp_out;   // scratch until final deform write
  float* co = fA;

  k_prep<<<dim3(1275), 256, 0, stream>>>(w1a, wT1a, w1c, wT1c, w2, wT2,
                                         w_off, wToff, w_dcn, wTd, sbuf);
  // merged resize + x_main transpose into T288
  k_inT<<<dim3(HW / 64, 9, B), 256, 0, stream>>>(inpfeat, x_main, T288);
  k_conv1x1_mfma<288, 0><<<dim3(HW / 128, 4, B), 256, 0, stream>>>(T288, wT1a, b1a, fA);
  // gn1: partial stats + f32-only apply (in-place on fA)
  k_gn_stats_part<<<dim3(GN, B, 4), 256, 0, stream>>>(fA, ssum1, ssq1);
  k_gnt<2><<<dim3(HW / 64, B, 4), 256, 0, stream>>>(fA, ssum1, ssq1, g1, be1, nullptr, fA);
  // dw7 (+ fused gn2 partial stats)
  k_dw7<<<dim3(HW / 1024, C, B), 256, 0, stream>>>(fA, w1b, b1b, fB, ssum2, ssq2);
  k_gnt<0><<<dim3(HW / 64, B, 4), 256, 0, stream>>>(fB, ssum2, ssq2, g2, be2, T2, nullptr);
  // conv1c: bf16 transposed output straight into Tc
  k_conv1x1_mfma<256, 1><<<dim3(HW / 128, 4, B), 256, 0, stream>>>(T2, wT1c, b1c, Tc);
  k_mfma_conv9<256, 256><<<dim3(HW / 128, 4, B), 256, 0, stream>>>(Tc, wT2, b2, fB);
  // gn3: partial stats + (T2 + f32 off_out)
  k_gn_stats_part<<<dim3(GN, B, 4), 256, 0, stream>>>(fB, ssum3, ssq3);
  k_gnt<1><<<dim3(HW / 64, B, 4), 256, 0, stream>>>(fB, ssum3, ssq3, g3, be3, T2, off_out);
  k_mfma_conv9<256, 216><<<dim3(HW / 128, 4, B), 256, 0, stream>>>(T2, wToff, b_off, co);
  // T288 dead -> reuse as xmT [B][HW][256] bf16
  k_transpose<<<dim3(HW / 64, 8, B), 256, 0, stream>>>(x_main, T288, C, 256, 0);
  k_deform_mfma<<<dim3(HW / 32, B), 512, 0, stream>>>(T288, co, wTd, b_dcn, warp_out);
}